// Round 15
// baseline (293.885 us; speedup 1.0000x reference)
//
#include <hip/hip_runtime.h>
#include <hip/hip_bf16.h>
#include <hip/hip_cooperative_groups.h>

namespace cg = cooperative_groups;

#define IN_F   1024
#define OUT_F  64
#define INTER  32
#define BATCH  512
#define NCOL   2048              // OUT_F * INTER
#define OUT_W  1088              // IN_F + OUT_F
#define SCREEN_T 25.0f           // drop terms with dist>=25: error <= 512*e^-25 ~ 7e-9
#define LIST_CAP 2048

typedef short bf16x8 __attribute__((ext_vector_type(8)));  // 8 bf16 (4 VGPRs)
typedef float f32x4  __attribute__((ext_vector_type(4)));  // 4 fp32

__device__ __forceinline__ unsigned short f2bf(float v) {
    __hip_bfloat16 h = __float2bfloat16(v);
    return *reinterpret_cast<unsigned short*>(&h);
}

// One cooperative kernel, 512 blocks x 256 threads, phases separated by grid.sync().
// R14 post-mortem: kernels total ~15us but 4 dispatches cost ~35us of launch gaps;
// the 42us ws-poison fill is harness-fixed. Fusion attacks the gaps.
__global__ __launch_bounds__(256, 2) void fused_kernel(const float* __restrict__ x,
                                                       const float* __restrict__ T,
                                                       float* __restrict__ out,
                                                       unsigned short* __restrict__ xb,
                                                       unsigned short* __restrict__ Bt,
                                                       float* __restrict__ Mt,
                                                       float* __restrict__ s) {
    cg::grid_group grid = cg::this_grid();
    const int bid = blockIdx.x;          // 0..511
    const int tid = threadIdx.x;

    __shared__ unsigned short ldsT[64][72];   // prep transpose staging (9216 B)
    __shared__ float  s_lds[256 * 4];         // screen: 256 quarter-sum vectors (4 KB)
    __shared__ unsigned int list[LIST_CAP];   // screen survivor list (8 KB)
    __shared__ int cnt;

    // ---------------- Phase A: prep (2 units/block of the old 1024-block grid) ----------
    #pragma unroll
    for (int ui = 0; ui < 2; ++ui) {
        const int u = bid * 2 + ui;
        if (u < BATCH) {
            // x-row: copy to out, init feature cols to 1.0 (diagonal exp(0) term), cast to xb
            const int r = u;
            const float4 v = ((const float4*)(x + (size_t)r * IN_F))[tid];
            *(float4*)(out + (size_t)r * OUT_W + tid * 4) = v;
            unsigned short h[4] = {f2bf(v.x), f2bf(v.y), f2bf(v.z), f2bf(v.w)};
            *(uint2*)(xb + (size_t)r * IN_F + tid * 4) = *(uint2*)h;
            if (tid < OUT_F / 4)
                *(float4*)(out + (size_t)r * OUT_W + IN_F + tid * 4) = make_float4(1.f, 1.f, 1.f, 1.f);
        } else {
            // T transpose tile: T[k][n] fp32 -> Bt[n][k] bf16
            __syncthreads();                  // ldsT reuse across ui iterations
            const int bidT = u - BATCH;
            const int n0 = (bidT & 31) * 64;
            const int k0 = (bidT >> 5) * 64;
            const int nl = tid & 63;
            const int kc = (tid >> 6) * 16;
            unsigned short uu[16];
            #pragma unroll
            for (int j = 0; j < 16; ++j)
                uu[j] = f2bf(T[(size_t)(k0 + kc + j) * NCOL + n0 + nl]);
            *(uint4*)&ldsT[nl][kc]     = *(uint4*)&uu[0];
            *(uint4*)&ldsT[nl][kc + 8] = *(uint4*)&uu[8];
            __syncthreads();
            const int n2  = tid >> 2;
            const int kc2 = (tid & 3) * 16;
            uint4 a = *(uint4*)&ldsT[n2][kc2];
            uint4 b = *(uint4*)&ldsT[n2][kc2 + 8];
            unsigned short* dst = Bt + (size_t)(n0 + n2) * IN_F + k0 + kc2;
            *(uint4*)dst       = a;
            *(uint4*)(dst + 8) = b;
        }
    }
    grid.sync();

    // ---------------- Phase B: GEMM (bf16 MFMA, no LDS), Mt[o][b][k] f32 ----------------
    {
        const int bx = bid & 63, by = bid >> 6;
        const int wave = tid >> 6, lane = tid & 63;
        const int quad = lane >> 4, lr = lane & 15;
        const int m0 = (by * 4 + wave) * 16;
        const int n0 = bx * 32;

        const unsigned short* pA  = xb + (size_t)(m0 + lr) * IN_F + quad * 8;
        const unsigned short* pB0 = Bt + (size_t)(n0 + lr) * IN_F + quad * 8;
        const unsigned short* pB1 = pB0 + 16 * IN_F;

        f32x4 acc0 = {0.f, 0.f, 0.f, 0.f};
        f32x4 acc1 = {0.f, 0.f, 0.f, 0.f};
        #pragma unroll 8
        for (int k0 = 0; k0 < IN_F; k0 += 32) {
            bf16x8 a  = *(const bf16x8*)(pA + k0);
            bf16x8 b0 = *(const bf16x8*)(pB0 + k0);
            bf16x8 b1 = *(const bf16x8*)(pB1 + k0);
            acc0 = __builtin_amdgcn_mfma_f32_16x16x32_bf16(a, b0, acc0, 0, 0, 0);
            acc1 = __builtin_amdgcn_mfma_f32_16x16x32_bf16(a, b1, acc1, 0, 0, 0);
        }
        // C/D: col = lane&15, row = quad*4 + r
        float* base = Mt + (size_t)(n0 >> 5) * (BATCH * INTER) + (size_t)(m0 + quad * 4) * INTER;
        #pragma unroll
        for (int r = 0; r < 4; ++r) {
            base[r * INTER + lr]      = acc0[r];
            base[r * INTER + 16 + lr] = acc1[r];
        }
    }
    grid.sync();

    // ---------------- Phase C: quarter sums s[o][b][q] ----------------
    {
        const int gid = bid * 256 + tid;      // 131072 = 32768 rows x 4 quarters
        const int row = gid >> 2;
        const int q   = gid & 3;
        const float4* p = (const float4*)(Mt + (size_t)row * INTER + q * 8);
        const float4 v0 = p[0], v1 = p[1];
        s[(size_t)row * 4 + q] = ((v0.x + v0.y) + (v0.z + v0.w)) + ((v1.x + v1.y) + (v1.z + v1.w));
    }
    grid.sync();

    // ---------------- Phase D: branchless screen + survivor list (2 bs-units/block) --------
    {
        const int ac = bid & 7;
        const int o  = bid >> 3;
        const int lane = tid & 63;
        const int wave = tid >> 6;
        const int a    = ac * 64 + lane;
        const float* slabM = Mt + (size_t)o * (BATCH * INTER);
        const float* slabS = s + (size_t)o * (BATCH * 4);
        const float4 sa = ((const float4*)slabS)[a];   // coalesced global

        for (int bs = 0; bs < 2; ++bs) {
            __syncthreads();                  // s_lds/list reuse across bs iterations
            *(float4*)&s_lds[tid * 4] = ((const float4*)slabS)[bs * 256 + tid];
            if (tid == 0) cnt = 0;
            __syncthreads();

            const int b0 = bs * 256 + wave * 64;
            #pragma unroll 8
            for (int j = 0; j < 64; ++j) {
                const float4 sb = *(const float4*)&s_lds[(wave * 64 + j) * 4];  // broadcast
                const float L = fabsf(sa.x - sb.x) + fabsf(sa.y - sb.y)
                              + fabsf(sa.z - sb.z) + fabsf(sa.w - sb.w);
                const int b = b0 + j;
                if (L < SCREEN_T && b != a) {         // ~never taken: append only
                    const int idx = atomicAdd(&cnt, 1);
                    if (idx < LIST_CAP) list[idx] = ((unsigned)lane << 16) | (unsigned)b;
                }
            }
            __syncthreads();

            const int n = min(cnt, LIST_CAP);
            for (int i = tid; i < n; i += 256) {      // expected n == 0
                const unsigned v = list[i];
                const int aa = ac * 64 + (int)(v >> 16);
                const int bb = (int)(v & 0xffffu);
                const float* pa = slabM + (size_t)aa * INTER;
                const float* pb = slabM + (size_t)bb * INTER;
                float d0 = 0.f, d1 = 0.f, d2 = 0.f, d3 = 0.f;
                #pragma unroll
                for (int k = 0; k < INTER; k += 4) {
                    const float4 va = *(const float4*)(pa + k);
                    const float4 vb = *(const float4*)(pb + k);
                    d0 += fabsf(va.x - vb.x);
                    d1 += fabsf(va.y - vb.y);
                    d2 += fabsf(va.z - vb.z);
                    d3 += fabsf(va.w - vb.w);
                }
                atomicAdd(&out[(size_t)aa * OUT_W + IN_F + o], __expf(-((d0 + d1) + (d2 + d3))));
            }
        }
    }
}

extern "C" void kernel_launch(void* const* d_in, const int* in_sizes, int n_in,
                              void* d_out, int out_size, void* d_ws, size_t ws_size,
                              hipStream_t stream) {
    const float* x = (const float*)d_in[0];   // [512,1024] fp32
    const float* T = (const float*)d_in[1];   // [1024,2048] fp32 row-major (k-major)
    float* out = (float*)d_out;               // [512,1088] fp32

    // ws layout: xb (1MB) | Bt (4MB) | Mt (4MB f32) | s (512KB) = 9.5MB
    unsigned short* xb = (unsigned short*)d_ws;                          // [512][1024] bf16
    unsigned short* Bt = (unsigned short*)((char*)d_ws + (1u << 20));    // [2048][1024] bf16
    float*          Mt = (float*)((char*)d_ws + (5u << 20));             // [64][512][32] f32
    float*          s  = (float*)((char*)d_ws + (9u << 20));             // [64][512][4] f32

    void* args[] = {(void*)&x, (void*)&T, (void*)&out, (void*)&xb,
                    (void*)&Bt, (void*)&Mt, (void*)&s};
    hipLaunchCooperativeKernel((const void*)fused_kernel, dim3(512), dim3(256),
                               args, 0, stream);
}

// Round 16
// 101.654 us; speedup vs baseline: 2.8910x; 2.8910x over previous
//
#include <hip/hip_runtime.h>
#include <hip/hip_bf16.h>

#define IN_F   1024
#define OUT_F  64
#define INTER  32
#define BATCH  512
#define NCOL   2048              // OUT_F * INTER
#define OUT_W  1088              // IN_F + OUT_F
#define SCREEN_T 25.0f           // drop terms with dist>=25: error <= 512*e^-25 ~ 7e-9
#define LIST_CAP 2048

typedef short bf16x8 __attribute__((ext_vector_type(8)));  // 8 bf16 (4 VGPRs)
typedef float f32x4  __attribute__((ext_vector_type(4)));  // 4 fp32

__device__ __forceinline__ unsigned short f2bf(float v) {
    __hip_bfloat16 h = __float2bfloat16(v);
    return *reinterpret_cast<unsigned short*>(&h);
}

// ---------------- Prep: copy x -> out, init feature cols to 1.0 (diagonal term),
//                  cast x -> xb, transpose T -> Bt ----------------
// R15 post-mortem: cooperative grid.sync() costs ~70us/sync on 8 non-coherent XCDs
// (fused kernel hit 223us, VALUBusy 2%) -> reverted to separate dispatches.
__global__ __launch_bounds__(256) void prep_kernel(const float* __restrict__ x,
                                                   const float* __restrict__ T,
                                                   float* __restrict__ out,
                                                   unsigned short* __restrict__ xb,
                                                   unsigned short* __restrict__ Bt) {
    const int tid = threadIdx.x;
    if (blockIdx.x < BATCH) {
        const int r = blockIdx.x;
        const float4 v = ((const float4*)(x + (size_t)r * IN_F))[tid];
        *(float4*)(out + (size_t)r * OUT_W + tid * 4) = v;
        unsigned short h[4] = {f2bf(v.x), f2bf(v.y), f2bf(v.z), f2bf(v.w)};
        *(uint2*)(xb + (size_t)r * IN_F + tid * 4) = *(uint2*)h;
        if (tid < OUT_F / 4)   // exp(0)=1 self-term baked in; screen adds rare survivors only
            *(float4*)(out + (size_t)r * OUT_W + IN_F + tid * 4) = make_float4(1.f, 1.f, 1.f, 1.f);
    } else {
        __shared__ unsigned short ldsT[64][72];   // [n][k], row stride 144B (16B-aligned)
        const int bid = blockIdx.x - BATCH;
        const int n0 = (bid & 31) * 64;
        const int k0 = (bid >> 5) * 64;
        const int nl = tid & 63;
        const int kc = (tid >> 6) * 16;
        unsigned short u[16];
        #pragma unroll
        for (int j = 0; j < 16; ++j)
            u[j] = f2bf(T[(size_t)(k0 + kc + j) * NCOL + n0 + nl]);
        *(uint4*)&ldsT[nl][kc]     = *(uint4*)&u[0];
        *(uint4*)&ldsT[nl][kc + 8] = *(uint4*)&u[8];
        __syncthreads();
        const int n2  = tid >> 2;
        const int kc2 = (tid & 3) * 16;
        uint4 a = *(uint4*)&ldsT[n2][kc2];
        uint4 b = *(uint4*)&ldsT[n2][kc2 + 8];
        unsigned short* dst = Bt + (size_t)(n0 + n2) * IN_F + k0 + kc2;
        *(uint4*)dst       = a;
        *(uint4*)(dst + 8) = b;
    }
}

// ---------------- GEMM (bf16 MFMA, no LDS, no barriers), Mt[o][b][k] f32 ----------------
__global__ __launch_bounds__(256) void gemm_kernel(const unsigned short* __restrict__ xb,
                                                   const unsigned short* __restrict__ Bt,
                                                   float* __restrict__ Mt) {
    const int tid  = threadIdx.x;
    const int wave = tid >> 6, lane = tid & 63;
    const int quad = lane >> 4, lr = lane & 15;
    const int m0 = (blockIdx.y * 4 + wave) * 16;
    const int n0 = blockIdx.x * 32;

    const unsigned short* pA  = xb + (size_t)(m0 + lr) * IN_F + quad * 8;
    const unsigned short* pB0 = Bt + (size_t)(n0 + lr) * IN_F + quad * 8;
    const unsigned short* pB1 = pB0 + 16 * IN_F;

    f32x4 acc0 = {0.f, 0.f, 0.f, 0.f};
    f32x4 acc1 = {0.f, 0.f, 0.f, 0.f};
    #pragma unroll 8
    for (int k0 = 0; k0 < IN_F; k0 += 32) {
        bf16x8 a  = *(const bf16x8*)(pA + k0);
        bf16x8 b0 = *(const bf16x8*)(pB0 + k0);
        bf16x8 b1 = *(const bf16x8*)(pB1 + k0);
        acc0 = __builtin_amdgcn_mfma_f32_16x16x32_bf16(a, b0, acc0, 0, 0, 0);
        acc1 = __builtin_amdgcn_mfma_f32_16x16x32_bf16(a, b1, acc1, 0, 0, 0);
    }
    // C/D: col = lane&15, row = quad*4 + r. Output Mt[o][b][k].
    float* base = Mt + (size_t)(n0 >> 5) * (BATCH * INTER) + (size_t)(m0 + quad * 4) * INTER;
    #pragma unroll
    for (int r = 0; r < 4; ++r) {
        base[r * INTER + lr]      = acc0[r];
        base[r * INTER + 16 + lr] = acc1[r];
    }
}

// ---------------- Screen with integrated quarter sums ----------------
// Block (ac,o) computes ALL 2048 quarter-sums of its o-slab from Mt (L2-hot, 64KB) into
// LDS, then screens a in [ac*64,+64) x all 512 b (wave covers 128 b). dist >= L =
// sum_q |s_a,q - s_b,q|; L >= T => dropped (error <= 512e^-25). Survivors (expected 0;
// diagonal excluded, baked into out=1.0 by prep) go to a deferred LDS list.
// Eliminates the separate sums dispatch + the s global buffer (R14: 4 -> 3 dispatches).
__global__ __launch_bounds__(256, 4) void screen_kernel(const float* __restrict__ Mt,
                                                        float* __restrict__ out) {
    const int o    = blockIdx.y;
    const int ac   = blockIdx.x;
    const int tid  = threadIdx.x;
    const int lane = tid & 63;
    const int wave = tid >> 6;
    const int a    = ac * 64 + lane;
    const float* slabM = Mt + (size_t)o * (BATCH * INTER);

    __shared__ float s_lds[BATCH * 4];   // 8 KB: all 512 b quarter-sum vectors
    __shared__ unsigned int list[LIST_CAP];
    __shared__ int cnt;
    if (tid == 0) cnt = 0;

    #pragma unroll
    for (int i = 0; i < 8; ++i) {        // 2048 quarters, 8 per thread
        const int qg  = i * 256 + tid;
        const int row = qg >> 2, q = qg & 3;
        const float4* p = (const float4*)(slabM + (size_t)row * INTER + q * 8);
        const float4 v0 = p[0], v1 = p[1];
        s_lds[qg] = ((v0.x + v0.y) + (v0.z + v0.w)) + ((v1.x + v1.y) + (v1.z + v1.w));
    }
    __syncthreads();

    const float4 sa = *(const float4*)&s_lds[a * 4];
    const int b0 = wave * 128;           // wave covers 128 b's
    #pragma unroll 8
    for (int j = 0; j < 128; ++j) {
        const float4 sb = *(const float4*)&s_lds[(b0 + j) * 4];  // broadcast ds_read_b128
        const float L = fabsf(sa.x - sb.x) + fabsf(sa.y - sb.y)
                      + fabsf(sa.z - sb.z) + fabsf(sa.w - sb.w);
        const int b = b0 + j;
        if (L < SCREEN_T && b != a) {    // ~never taken: append only
            const int idx = atomicAdd(&cnt, 1);
            if (idx < LIST_CAP) list[idx] = ((unsigned)lane << 16) | (unsigned)b;
        }
    }
    __syncthreads();

    const int n = min(cnt, LIST_CAP);
    for (int i = tid; i < n; i += 256) { // expected n == 0
        const unsigned v = list[i];
        const int aa = ac * 64 + (int)(v >> 16);
        const int bb = (int)(v & 0xffffu);
        const float* pa = slabM + (size_t)aa * INTER;
        const float* pb = slabM + (size_t)bb * INTER;
        float d0 = 0.f, d1 = 0.f, d2 = 0.f, d3 = 0.f;
        #pragma unroll
        for (int k = 0; k < INTER; k += 4) {
            const float4 va = *(const float4*)(pa + k);
            const float4 vb = *(const float4*)(pb + k);
            d0 += fabsf(va.x - vb.x);
            d1 += fabsf(va.y - vb.y);
            d2 += fabsf(va.z - vb.z);
            d3 += fabsf(va.w - vb.w);
        }
        atomicAdd(&out[(size_t)aa * OUT_W + IN_F + o], __expf(-((d0 + d1) + (d2 + d3))));
    }
}

extern "C" void kernel_launch(void* const* d_in, const int* in_sizes, int n_in,
                              void* d_out, int out_size, void* d_ws, size_t ws_size,
                              hipStream_t stream) {
    const float* x = (const float*)d_in[0];   // [512,1024] fp32
    const float* T = (const float*)d_in[1];   // [1024,2048] fp32 row-major (k-major)
    float* out = (float*)d_out;               // [512,1088] fp32

    // ws layout: xb (1MB) | Bt (4MB) | Mt (4MB f32) = 9MB
    unsigned short* xb = (unsigned short*)d_ws;                          // [512][1024] bf16
    unsigned short* Bt = (unsigned short*)((char*)d_ws + (1u << 20));    // [2048][1024] bf16
    float*          Mt = (float*)((char*)d_ws + (5u << 20));             // [64][512][32] f32

    prep_kernel<<<1024, 256, 0, stream>>>(x, T, out, xb, Bt);

    dim3 ggrid(NCOL / 32, BATCH / 64);        // 64 x 8 = 512 blocks
    gemm_kernel<<<ggrid, 256, 0, stream>>>(xb, Bt, Mt);

    dim3 sgrid(BATCH / 64, OUT_F);            // 8 x 64 = 512 blocks
    screen_kernel<<<sgrid, 256, 0, stream>>>(Mt, out);
}

// Round 17
// 97.725 us; speedup vs baseline: 3.0073x; 1.0402x over previous
//
#include <hip/hip_runtime.h>
#include <hip/hip_bf16.h>

#define IN_F   1024
#define OUT_F  64
#define INTER  32
#define BATCH  512
#define NCOL   2048              // OUT_F * INTER
#define OUT_W  1088              // IN_F + OUT_F
#define SCREEN_T 25.0f           // drop terms with dist>=25: error <= 512*e^-25 ~ 7e-9
#define LIST_CAP 2048

typedef short bf16x8 __attribute__((ext_vector_type(8)));  // 8 bf16 (4 VGPRs)
typedef float f32x4  __attribute__((ext_vector_type(4)));  // 4 fp32

union AB { unsigned short h[8]; bf16x8 v; };

__device__ __forceinline__ unsigned short f2bf(float v) {
    __hip_bfloat16 h = __float2bfloat16(v);
    return *reinterpret_cast<unsigned short*>(&h);
}

// ---------------- K1: GEMM direct from raw x/T (+ prep-x rider blocks) ----------------
// R16 post-mortem: dispatch gaps (~10us each) dominate the controllable budget. This kernel
// absorbs prep: A converts x fp32->bf16 in-register (same RNE as prep -> Mt bit-identical);
// B stages T[k0:k0+64][n0:n0+32] into LDS bf16 [n][k] (stride 72 halves: 16B-aligned
// ds_read_b128 fragments; b16 scatter writes ~8-way conflict, small total).
// Blocks 0..511: gemm (bx=o 0..63, by 0..7). Blocks 512..1023: x->out copy + 1.0 init.
__global__ __launch_bounds__(256, 4) void gemm_kernel(const float* __restrict__ x,
                                                      const float* __restrict__ T,
                                                      float* __restrict__ out,
                                                      float* __restrict__ Mt) {
    const int tid = threadIdx.x;
    if (blockIdx.x >= 512) {                 // prep-x rider: copy + feature-col init
        const int r = blockIdx.x - 512;
        const float4 v = ((const float4*)(x + (size_t)r * IN_F))[tid];
        *(float4*)(out + (size_t)r * OUT_W + tid * 4) = v;
        if (tid < OUT_F / 4)   // exp(0)=1 self-term baked in; screen adds rare survivors only
            *(float4*)(out + (size_t)r * OUT_W + IN_F + tid * 4) = make_float4(1.f, 1.f, 1.f, 1.f);
        return;
    }

    __shared__ unsigned short Bs[32][72];    // [n][k-within-stage], 4608 B
    const int bx = blockIdx.x & 63, by = blockIdx.x >> 6;
    const int wave = tid >> 6, lane = tid & 63;
    const int quad = lane >> 4, lr = lane & 15;
    const int m0 = (by * 4 + wave) * 16;
    const int n0 = bx * 32;

    const float* pA = x + (size_t)(m0 + lr) * IN_F + quad * 8;
    const int tc = tid & 7;                  // staging n-group: n = tc*4 .. +3
    const int tk = tid >> 3;                 // staging k-row within pass: 0..31

    f32x4 acc0 = {0.f, 0.f, 0.f, 0.f};
    f32x4 acc1 = {0.f, 0.f, 0.f, 0.f};

    for (int k0 = 0; k0 < IN_F; k0 += 64) {
        __syncthreads();                     // previous stage's reads done
        #pragma unroll
        for (int p = 0; p < 2; ++p) {        // stage T[k0..+64][n0..+32] -> Bs[n][k] bf16
            const int kk = tk + p * 32;
            const float4 tv = *(const float4*)(T + (size_t)(k0 + kk) * NCOL + n0 + tc * 4);
            Bs[tc * 4 + 0][kk] = f2bf(tv.x);
            Bs[tc * 4 + 1][kk] = f2bf(tv.y);
            Bs[tc * 4 + 2][kk] = f2bf(tv.z);
            Bs[tc * 4 + 3][kk] = f2bf(tv.w);
        }
        __syncthreads();
        #pragma unroll
        for (int s = 0; s < 2; ++s) {        // two 32-K MFMA steps per stage
            const float4 lo = *(const float4*)(pA + k0 + s * 32);
            const float4 hi = *(const float4*)(pA + k0 + s * 32 + 4);
            AB a;
            a.h[0] = f2bf(lo.x); a.h[1] = f2bf(lo.y); a.h[2] = f2bf(lo.z); a.h[3] = f2bf(lo.w);
            a.h[4] = f2bf(hi.x); a.h[5] = f2bf(hi.y); a.h[6] = f2bf(hi.z); a.h[7] = f2bf(hi.w);
            const int ks = s * 32 + quad * 8;
            const bf16x8 b0 = *(const bf16x8*)&Bs[lr][ks];        // ds_read_b128, 16B-aligned
            const bf16x8 b1 = *(const bf16x8*)&Bs[lr + 16][ks];
            acc0 = __builtin_amdgcn_mfma_f32_16x16x32_bf16(a.v, b0, acc0, 0, 0, 0);
            acc1 = __builtin_amdgcn_mfma_f32_16x16x32_bf16(a.v, b1, acc1, 0, 0, 0);
        }
    }
    // C/D: col = lane&15, row = quad*4 + r. Output Mt[o=bx][b][k].
    float* base = Mt + (size_t)bx * (BATCH * INTER) + (size_t)(m0 + quad * 4) * INTER;
    #pragma unroll
    for (int r = 0; r < 4; ++r) {
        base[r * INTER + lr]      = acc0[r];
        base[r * INTER + 16 + lr] = acc1[r];
    }
}

// ---------------- K2: Screen with integrated quarter sums ----------------
// Block (ac,o): quarter-sums of the o-slab (L2-hot) into LDS, then screen a x all 512 b.
// dist >= L = sum_q |s_a,q - s_b,q|; L >= T => dropped (error <= 512e^-25). Survivors
// (expected 0; diagonal baked into out=1.0) go to a deferred LDS list.
__global__ __launch_bounds__(256, 4) void screen_kernel(const float* __restrict__ Mt,
                                                        float* __restrict__ out) {
    const int o    = blockIdx.y;
    const int ac   = blockIdx.x;
    const int tid  = threadIdx.x;
    const int lane = tid & 63;
    const int wave = tid >> 6;
    const int a    = ac * 64 + lane;
    const float* slabM = Mt + (size_t)o * (BATCH * INTER);

    __shared__ float s_lds[BATCH * 4];   // 8 KB: all 512 b quarter-sum vectors
    __shared__ unsigned int list[LIST_CAP];
    __shared__ int cnt;
    if (tid == 0) cnt = 0;

    #pragma unroll
    for (int i = 0; i < 8; ++i) {        // 2048 quarters, 8 per thread
        const int qg  = i * 256 + tid;
        const int row = qg >> 2, q = qg & 3;
        const float4* p = (const float4*)(slabM + (size_t)row * INTER + q * 8);
        const float4 v0 = p[0], v1 = p[1];
        s_lds[qg] = ((v0.x + v0.y) + (v0.z + v0.w)) + ((v1.x + v1.y) + (v1.z + v1.w));
    }
    __syncthreads();

    const float4 sa = *(const float4*)&s_lds[a * 4];
    const int b0 = wave * 128;           // wave covers 128 b's
    #pragma unroll 8
    for (int j = 0; j < 128; ++j) {
        const float4 sb = *(const float4*)&s_lds[(b0 + j) * 4];  // broadcast ds_read_b128
        const float L = fabsf(sa.x - sb.x) + fabsf(sa.y - sb.y)
                      + fabsf(sa.z - sb.z) + fabsf(sa.w - sb.w);
        const int b = b0 + j;
        if (L < SCREEN_T && b != a) {    // ~never taken: append only
            const int idx = atomicAdd(&cnt, 1);
            if (idx < LIST_CAP) list[idx] = ((unsigned)lane << 16) | (unsigned)b;
        }
    }
    __syncthreads();

    const int n = min(cnt, LIST_CAP);
    for (int i = tid; i < n; i += 256) { // expected n == 0
        const unsigned v = list[i];
        const int aa = ac * 64 + (int)(v >> 16);
        const int bb = (int)(v & 0xffffu);
        const float* pa = slabM + (size_t)aa * INTER;
        const float* pb = slabM + (size_t)bb * INTER;
        float d0 = 0.f, d1 = 0.f, d2 = 0.f, d3 = 0.f;
        #pragma unroll
        for (int k = 0; k < INTER; k += 4) {
            const float4 va = *(const float4*)(pa + k);
            const float4 vb = *(const float4*)(pb + k);
            d0 += fabsf(va.x - vb.x);
            d1 += fabsf(va.y - vb.y);
            d2 += fabsf(va.z - vb.z);
            d3 += fabsf(va.w - vb.w);
        }
        atomicAdd(&out[(size_t)aa * OUT_W + IN_F + o], __expf(-((d0 + d1) + (d2 + d3))));
    }
}

extern "C" void kernel_launch(void* const* d_in, const int* in_sizes, int n_in,
                              void* d_out, int out_size, void* d_ws, size_t ws_size,
                              hipStream_t stream) {
    const float* x = (const float*)d_in[0];   // [512,1024] fp32
    const float* T = (const float*)d_in[1];   // [1024,2048] fp32 row-major (k-major)
    float* out = (float*)d_out;               // [512,1088] fp32
    float* Mt  = (float*)d_ws;                // [64][512][32] f32 (4 MB)

    gemm_kernel<<<1024, 256, 0, stream>>>(x, T, out, Mt);   // 512 gemm + 512 prep-x blocks

    dim3 sgrid(BATCH / 64, OUT_F);            // 8 x 64 = 512 blocks
    screen_kernel<<<sgrid, 256, 0, stream>>>(Mt, out);
}